// Round 5
// baseline (231.471 us; speedup 1.0000x reference)
//
#include <hip/hip_runtime.h>
#include <hip/hip_bf16.h>
#include <math.h>

// Problem constants
#define BATCH 2
#define SLEN  2048
#define DIN   1024
#define DMODEL 1024
#define NHEAD 16
#define HD    64
#define E3    3072   // 3*DMODEL, row width of qkv

typedef unsigned short us;
typedef _Float16 f16;
typedef __attribute__((ext_vector_type(8))) _Float16 f16x8;
typedef __attribute__((ext_vector_type(8))) unsigned short us8;
typedef __attribute__((ext_vector_type(4))) unsigned short us4;
typedef __attribute__((ext_vector_type(4))) float f32x4;
typedef __attribute__((ext_vector_type(16))) float f32x16;
typedef __attribute__((ext_vector_type(4))) unsigned int u32x4;

// 0.125 (1/sqrt(HD)) * log2(e): folded into Q at qkv-GEMM epilogue so the
// attention softmax is a bare exp2 of the raw MFMA score.
#define QSCALE 0.18033688011112042f

__device__ __forceinline__ us f16bits(float x) {
    const f16 h = (f16)x;
    return __builtin_bit_cast(us, h);
}

__device__ __forceinline__ unsigned int pkrtz(float a, float b) {
    return __builtin_bit_cast(unsigned int, __builtin_amdgcn_cvt_pkrtz(a, b));
}

// v_permlane32_swap_b32: a' = {a.lo, b.lo}, b' = {a.hi, b.hi}
__device__ __forceinline__ void plswap(unsigned int& a, unsigned int& b) {
    asm volatile("v_permlane32_swap_b32 %0, %1" : "+v"(a), "+v"(b));
}

__device__ __forceinline__ void barrier_raw() {
    asm volatile("s_barrier" ::: "memory");
}

// async 16B global->LDS (lane i deposits at ldsbase + i*16)
#define GLL16(g, l)                                                                     \
    __builtin_amdgcn_global_load_lds((const __attribute__((address_space(1))) unsigned int*)(g), \
                                     (__attribute__((address_space(3))) unsigned int*)(l), 16, 0, 0)

// ---------------- fp32 -> fp16 for x, w_qkv, w_o in one launch ----------------
__global__ __launch_bounds__(256) void cvt3_f16(
    const float* __restrict__ x, us* __restrict__ ox, int nx,
    const float* __restrict__ wq, us* __restrict__ owq, int nq,
    const float* __restrict__ wo, us* __restrict__ owo)
{
    int i = (blockIdx.x * 256 + threadIdx.x) * 8;
    const float* s;
    us* o;
    if (i < nx)           { s = x;  o = ox; }
    else if (i < nx + nq) { s = wq; o = owq; i -= nx; }
    else                  { s = wo; o = owo; i -= nx + nq; }
    const float4 f0 = *(const float4*)&s[i];
    const float4 f1 = *(const float4*)&s[i + 4];
    const float v[8] = {f0.x, f0.y, f0.z, f0.w, f1.x, f1.y, f1.z, f1.w};
    us8 h;
#pragma unroll
    for (int j = 0; j < 8; ++j) h[j] = f16bits(v[j]);
    *(us8*)&o[i] = h;
}

// ---------------- 128xBN double-buffered counted-vmcnt MFMA GEMM ----------------
// (unchanged from R3; see comments there)
#define GBK 64
#define GNT (DIN / GBK)   // 16 (both GEMMs have K=1024)

template <int BN, bool QKV_OUT>
__global__ __launch_bounds__(256) void gemm_db(
    const us* __restrict__ Am, const us* __restrict__ Bm,
    const float* __restrict__ bias, void* __restrict__ Cout,
    int M, int N, int K)
{
    constexpr int NJ  = BN / 32;    // n-frags per wave (4 or 2)
    constexpr int BGL = BN / 32;    // B-staging GLLs per wave (4 or 2)
    __shared__ __align__(16) us ldsA[2 * 128 * 64];
    __shared__ __align__(16) us ldsB[2 * BN * 64];

    const int t    = threadIdx.x;
    const int lane = t & 63;
    const int w    = t >> 6;        // wave 0..3
    const int ml   = lane & 15;
    const int quad = lane >> 4;
    const int msk  = ml & 7;
    const int wm   = w >> 1;
    const int wn   = w & 1;

    // XCD-aware bijective block swizzle (nwg % 8 == 0 for both grids)
    const int nbx = N / BN;
    const int nwg = (M >> 7) * nbx;
    int wg = blockIdx.y * nbx + blockIdx.x;
    wg = (wg & 7) * (nwg >> 3) + (wg >> 3);
    const int m0 = (wg / nbx) * 128;
    const int n0 = (wg % nbx) * BN;

    const int r8  = lane >> 3;
    const int xsw = ((lane & 7) ^ r8) * 8;
    const us* pA = Am + (size_t)(m0 + w * 32 + r8) * K + xsw;
    const int brow = (BN == 128) ? w * 32 : w * 16;
    const us* pB = Bm + (size_t)(n0 + brow + r8) * K + xsw;

#define STG_A(d, kk) do { _Pragma("unroll") for (int g = 0; g < 4; ++g) \
    GLL16(pA + (size_t)(8 * g) * K + (kk), &ldsA[(d) * 8192 + w * 2048 + g * 512]); } while (0)
#define STG_B(d, kk) do { _Pragma("unroll") for (int g = 0; g < BGL; ++g) \
    GLL16(pB + (size_t)(8 * g) * K + (kk), &ldsB[(d) * (BN * 64) + brow * 64 + g * 512]); } while (0)

#define LDA(d, mi, ks) __builtin_bit_cast(f16x8, *(const us8*)&ldsA[(d) * 8192 + (wm * 64 + (mi) * 16 + ml) * 64 + (((quad ^ msk) ^ ((ks) << 2)) * 8)])
#define LDB(d, nj, ks) __builtin_bit_cast(f16x8, *(const us8*)&ldsB[(d) * (BN * 64) + (wn * (BN / 2) + (nj) * 16 + ml) * 64 + (((quad ^ msk) ^ ((ks) << 2)) * 8)])

#define WAIT_BGL() do { if constexpr (BN == 128) asm volatile("s_waitcnt vmcnt(4)" ::: "memory"); \
                        else                     asm volatile("s_waitcnt vmcnt(2)" ::: "memory"); } while (0)

    f32x4 acc[4][NJ];
#pragma unroll
    for (int i = 0; i < 4; ++i)
#pragma unroll
        for (int j = 0; j < NJ; ++j) {
            acc[i][j][0] = 0.f; acc[i][j][1] = 0.f; acc[i][j][2] = 0.f; acc[i][j][3] = 0.f;
        }

    STG_A(0, 0); STG_B(0, 0);
    STG_B(1, GBK);
    WAIT_BGL();
    barrier_raw();

    for (int tt = 0; tt < GNT; ++tt) {
        const int d = tt & 1, e = d ^ 1;

        if (tt + 1 < GNT) STG_A(e, (tt + 1) * GBK);
        f16x8 bf[2][NJ];
#pragma unroll
        for (int ks = 0; ks < 2; ++ks)
#pragma unroll
            for (int nj = 0; nj < NJ; ++nj)
                bf[ks][nj] = LDB(d, nj, ks);
        f16x8 a0[2][2];
#pragma unroll
        for (int mi = 0; mi < 2; ++mi) {
            a0[mi][0] = LDA(d, mi, 0);
            a0[mi][1] = LDA(d, mi, 1);
        }
        __builtin_amdgcn_s_setprio(1);
#pragma unroll
        for (int ks = 0; ks < 2; ++ks)
#pragma unroll
            for (int nj = 0; nj < NJ; ++nj)
#pragma unroll
                for (int mi = 0; mi < 2; ++mi)
                    acc[mi][nj] = __builtin_amdgcn_mfma_f32_16x16x32_f16(a0[mi][ks], bf[ks][nj], acc[mi][nj], 0, 0, 0);
        __builtin_amdgcn_s_setprio(0);
        barrier_raw();

        if (tt + 2 < GNT) STG_B(d, (tt + 2) * GBK);
        f16x8 a1[2][2];
#pragma unroll
        for (int mi = 0; mi < 2; ++mi) {
            a1[mi][0] = LDA(d, mi + 2, 0);
            a1[mi][1] = LDA(d, mi + 2, 1);
        }
        __builtin_amdgcn_s_setprio(1);
#pragma unroll
        for (int ks = 0; ks < 2; ++ks)
#pragma unroll
            for (int nj = 0; nj < NJ; ++nj)
#pragma unroll
                for (int mi = 0; mi < 2; ++mi)
                    acc[mi + 2][nj] = __builtin_amdgcn_mfma_f32_16x16x32_f16(a1[mi][ks], bf[ks][nj], acc[mi + 2][nj], 0, 0, 0);
        __builtin_amdgcn_s_setprio(0);

        if (tt + 2 < GNT)      WAIT_BGL();
        else if (tt + 1 < GNT) asm volatile("s_waitcnt vmcnt(0)" ::: "memory");
        barrier_raw();
    }

    float bj[NJ], cs[NJ];
#pragma unroll
    for (int nj = 0; nj < NJ; ++nj) {
        const int col = n0 + wn * (BN / 2) + nj * 16 + ml;
        bj[nj] = bias[col];
        cs[nj] = (QKV_OUT && (col % 192) < 64) ? QSCALE : 1.0f;
    }
#pragma unroll
    for (int mi = 0; mi < 4; ++mi) {
#pragma unroll
        for (int r = 0; r < 4; ++r) {
            const size_t rowoff = (size_t)(m0 + wm * 64 + mi * 16 + quad * 4 + r) * N;
#pragma unroll
            for (int nj = 0; nj < NJ; ++nj) {
                const int col = n0 + wn * (BN / 2) + nj * 16 + ml;
                const float v = (acc[mi][nj][r] + bj[nj]) * cs[nj];
                if (QKV_OUT) ((us*)Cout)[rowoff + col] = f16bits(v);
                else         ((float*)Cout)[rowoff + col] = v;
            }
        }
    }
#undef STG_A
#undef STG_B
#undef LDA
#undef LDB
#undef WAIT_BGL
}

// ---------------- MFMA flash attention: K direct from global (L2), V-only LDS ----------------
// 8 waves, key-split (waves 0-3: chunks [0,16), 4-7: [16,32)), T12 in-register P,
// T1 XCD-owned bh grid. NEW (R5): K never touches LDS. The QK A-fragment
// (8 contiguous f16 at row c*64+kt*32+m32, col half*8+16s) is loaded straight
// from global into 32 VGPRs -- K is L2-resident (12 MB FETCH total) and the
// 4 waves of a split read identical lines (L1/L2 broadcast). Removes per
// chunk-wave: 8 ds_read_b128 + 2 ds_write_b128 (~55% of LDS traffic, the
// dominant pipe at ~17 us/CU) and one of the two chunk barriers:
//   chunk c: QK(c) from K-regs; reload K(c+1)->regs; exp2+pack;
//            write V(c+1)->buf e; prefetch V(c+2)->regs; PV(c) from buf d;
//            ONE barrier (orders V(c+1) write vs PV(c+1) read).
// K-regs single-buffered: reload issues after QK(c)'s last use, lands during
// exp2+PV+barrier (>= ~300 cyc > L2 latency ~200).
#define ABQ 128
#define ACH 64
#define NCH (SLEN / ACH)    // 32
#define NCH2 (NCH / 2)      // 16 chunks per split
#define LQA 72              // LDS row stride in fp16 elems
#define OSTR 68             // combine-scratch row stride in f32

__global__ __launch_bounds__(512, 4) void attn_mfma(
    const us* __restrict__ qkvh, us* __restrict__ vals)
{
    // Q 9216 | V dbuf 2 x (2 splits x 4608) = 27648 us = 55296 B (2 blk/CU)
    __shared__ __align__(16) us smem[27648];
    us* const Qs = smem;            // [0, 9216)
    us* const Vb0 = smem + 9216;    // [9216, 18432)
    us* const Vb1 = smem + 18432;   // [18432, 27648)

    const int t    = threadIdx.x;
    const int lane = t & 63;
    const int w    = t >> 6;        // wave 0..7
    const int sp   = w >> 2;        // key split 0/1
    const int wq4  = w & 3;         // q-group within split
    const int t2   = t & 255;       // thread id within split
    const int m32  = lane & 31;
    const int half = lane >> 5;

    // XCD-owning decomposition: xcd = wg&7; bh = ((wg>>7)<<3)|xcd; qi = (wg>>3)&15
    const int wg  = blockIdx.x;
    const int s9  = wg >> 3;
    const int bh  = ((s9 >> 4) << 3) | (wg & 7);
    const int b   = bh >> 4;
    const int h   = bh & 15;
    const int q0  = (s9 & 15) * ABQ;

    const size_t base = (size_t)b * SLEN * E3;
    const int qoff = h * 192;

    // V staging map (within split)
    const int k2  = t2 & 31;          // V: key PAIR (2*k2, 2*k2+1)
    const int d0v = (t2 >> 5) * 8;    // V: 8 dims/thread

    us* const myV0 = Vb0 + sp * 4608;
    us* const myV1 = Vb1 + sp * 4608;
    const int cg0 = sp * NCH2;

    // per-lane K fragment pointer: row m32 (+ kt*32 + chunk*64), col half*8 (+16s)
    const us* const gK = &qkvh[base + (size_t)m32 * E3 + qoff + 64 + half * 8];

    us8 kr[2][4];
#define LOADK(cgi) do { _Pragma("unroll") for (int kt = 0; kt < 2; ++kt) \
    _Pragma("unroll") for (int s = 0; s < 4; ++s) \
        kr[kt][s] = *(const us8*)&gK[(size_t)((cgi) * ACH + kt * 32) * E3 + 16 * s]; } while (0)

    // ---- stage Q (128 q x 64 d): 16 elems / thread ----
    {
        const int row = t >> 2;
        const int c0q = (t & 3) * 16;
        const us* g = &qkvh[base + (size_t)(q0 + row) * E3 + qoff + c0q];
        *(us8*)&Qs[row * LQA + c0q]     = *(const us8*)g;
        *(us8*)&Qs[row * LQA + c0q + 8] = *(const us8*)(g + 8);
    }

    // ---- prologue: K(0)->regs; V(0)->buf0; V(1)->regs ----
    LOADK(cg0);
    us8 vv0, vv1;
    {
        const us* gV = &qkvh[base + (size_t)(cg0 * ACH + 2 * k2) * E3 + qoff + 128 + d0v];
        vv0 = *(const us8*)gV; vv1 = *(const us8*)(gV + E3);
    }
#pragma unroll
    for (int j = 0; j < 8; ++j) {
        const unsigned int pv = (unsigned int)vv0[j] | ((unsigned int)vv1[j] << 16);
        *(unsigned int*)&myV0[(d0v + j) * LQA + 2 * k2] = pv;
    }
    {
        const us* gV = &qkvh[base + (size_t)((cg0 + 1) * ACH + 2 * k2) * E3 + qoff + 128 + d0v];
        vv0 = *(const us8*)gV; vv1 = *(const us8*)(gV + E3);
    }
    __syncthreads();   // Q + V(0) visible to all waves

    // Q B-frags: B[k=dim][n=q], q = wq4*32 + m32 (Q area live until epilogue reuse)
    f16x8 aq[4];
#pragma unroll
    for (int s = 0; s < 4; ++s)
        aq[s] = __builtin_bit_cast(f16x8, *(const us8*)&Qs[(wq4 * 32 + m32) * LQA + half * 8 + 16 * s]);

    f32x16 O[2];
#pragma unroll
    for (int dt = 0; dt < 2; ++dt)
#pragma unroll
        for (int r = 0; r < 16; ++r) O[dt][r] = 0.f;
    float lp[4] = {0.f, 0.f, 0.f, 0.f};

    for (int c = 0; c < NCH2; ++c) {
        us* const Vrd = (c & 1) ? myV1 : myV0;
        us* const Vwr = (c & 1) ? myV0 : myV1;

        // ---- S^T = K.Q^T from K-regs; exp2; T12 in-register P redistribution ----
        f16x8 pf[4];
#pragma unroll
        for (int kt = 0; kt < 2; ++kt) {
            f32x16 z;
#pragma unroll
            for (int r = 0; r < 16; ++r) z[r] = 0.f;
#pragma unroll
            for (int s = 0; s < 4; ++s)
                z = __builtin_amdgcn_mfma_f32_32x32x16_f16(
                        __builtin_bit_cast(f16x8, kr[kt][s]), aq[s], z, 0, 0, 0);
            float p[16];
#pragma unroll
            for (int r = 0; r < 16; ++r) {
                p[r] = __builtin_amdgcn_exp2f(z[r]);
                lp[r & 3] += p[r];
            }
            unsigned int a0 = pkrtz(p[0],  p[1]),  a1 = pkrtz(p[2],  p[3]);
            unsigned int b0 = pkrtz(p[4],  p[5]),  b1 = pkrtz(p[6],  p[7]);
            plswap(a0, b0); plswap(a1, b1);
            pf[2 * kt] = __builtin_bit_cast(f16x8, (u32x4){a0, a1, b0, b1});
            unsigned int e0 = pkrtz(p[8],  p[9]),  e1 = pkrtz(p[10], p[11]);
            unsigned int f0 = pkrtz(p[12], p[13]), f1 = pkrtz(p[14], p[15]);
            plswap(e0, f0); plswap(e1, f1);
            pf[2 * kt + 1] = __builtin_bit_cast(f16x8, (u32x4){e0, e1, f0, f1});
        }

        // ---- reload K-regs for next chunk (WAR on kr; lands during PV+barrier) ----
        if (c + 1 < NCH2) LOADK(cg0 + c + 1);

        // ---- write V(c+1) -> other buffer (readers retired at prev barrier) ----
        if (c + 1 < NCH2) {
#pragma unroll
            for (int j = 0; j < 8; ++j) {
                const unsigned int pv = (unsigned int)vv0[j] | ((unsigned int)vv1[j] << 16);
                *(unsigned int*)&Vwr[(d0v + j) * LQA + 2 * k2] = pv;
            }
        }
        // ---- prefetch V(c+2) -> regs ----
        if (c + 2 < NCH2) {
            const us* gV = &qkvh[base + (size_t)((cg0 + c + 2) * ACH + 2 * k2) * E3 + qoff + 128 + d0v];
            vv0 = *(const us8*)gV; vv1 = *(const us8*)(gV + E3);
        }

        // ---- O^T += V^T.P^T ----
#pragma unroll
        for (int dt = 0; dt < 2; ++dt) {
#pragma unroll
            for (int s = 0; s < 4; ++s) {
                const f16x8 av = __builtin_bit_cast(f16x8, *(const us8*)&Vrd[(dt * 32 + m32) * LQA + half * 8 + 16 * s]);
                O[dt] = __builtin_amdgcn_mfma_f32_32x32x16_f16(av, pf[s], O[dt], 0, 0, 0);
            }
        }

        __syncthreads();   // PV(c) V-reads retired; V(c+1) visible next chunk
    }

    const float lpart = (lp[0] + lp[1]) + (lp[2] + lp[3]);
    const float l = lpart + __shfl_xor(lpart, 32);
    const int ql = wq4 * 32 + m32;

    // ---- epilogue: combine the two key-splits through LDS (Q/V areas dead) ----
    __syncthreads();
    float* const Osc = (float*)smem;         // 128 x OSTR f32 (34816 B)
    float* const lsc = Osc + ABQ * OSTR;     // 128 f32

    if (sp == 1) {
#pragma unroll
        for (int dt = 0; dt < 2; ++dt) {
#pragma unroll
            for (int g = 0; g < 4; ++g) {
                const f32x4 o4 = {O[dt][g * 4], O[dt][g * 4 + 1], O[dt][g * 4 + 2], O[dt][g * 4 + 3]};
                *(f32x4*)&Osc[ql * OSTR + dt * 32 + 8 * g + 4 * half] = o4;
            }
        }
        if (half == 0) lsc[ql] = l;
    }
    __syncthreads();
    if (sp == 0) {
        const float rl = 1.0f / (l + lsc[ql]);
        const int sq = q0 + ql;
        const size_t rowbase = (size_t)(b * SLEN + sq) * DMODEL + h * HD;
#pragma unroll
        for (int dt = 0; dt < 2; ++dt) {
#pragma unroll
            for (int g = 0; g < 4; ++g) {
                const f32x4 part = *(const f32x4*)&Osc[ql * OSTR + dt * 32 + 8 * g + 4 * half];
                us4 o4;
#pragma unroll
                for (int r2 = 0; r2 < 4; ++r2)
                    o4[r2] = f16bits((O[dt][g * 4 + r2] + part[r2]) * rl);
                *(us4*)&vals[rowbase + dt * 32 + 8 * g + 4 * half] = o4;
            }
        }
    }
#undef LOADK
}

// ---------------- launch ----------------
extern "C" void kernel_launch(void* const* d_in, const int* in_sizes, int n_in,
                              void* d_out, int out_size, void* d_ws, size_t ws_size,
                              hipStream_t stream) {
    const float* x     = (const float*)d_in[0];
    const float* w_qkv = (const float*)d_in[1];
    const float* b_qkv = (const float*)d_in[2];
    const float* w_o   = (const float*)d_in[3];
    const float* b_o   = (const float*)d_in[4];
    float* out = (float*)d_out;

    const int M   = BATCH * SLEN;        // 4096
    const int XN  = M * DIN;             // 4,194,304
    const int WQN = E3 * DIN;            // 3,145,728
    const int WON = DMODEL * DMODEL;     // 1,048,576
    const size_t QKVN = (size_t)BATCH * SLEN * E3;

    us* qkvh = (us*)d_ws;                // fp16 qkv [QKVN]
    us* xh   = qkvh + QKVN;              // fp16 x [XN], reused for vals
    us* wq   = xh + XN;                  // fp16 w_qkv [WQN]
    us* wo   = wq + WQN;                 // fp16 w_o [WON]

    // 1) fp32 -> fp16 conversions, one launch
    cvt3_f16<<<dim3((XN + WQN + WON) / 2048), 256, 0, stream>>>(
        x, xh, XN, w_qkv, wq, WQN, w_o, wo);

    // 2) qkv = x @ w_qkv^T + b_qkv -> fp16 (Q cols pre-scaled by QSCALE)
    gemm_db<128, true><<<dim3(E3 / 128, M / 128), 256, 0, stream>>>(
        xh, wq, b_qkv, qkvh, M, E3, DIN);

    // 3) attention -> vals fp16 (reuse x plane; x is dead); 1D grid, XCD-owned bh
    us* vals = xh;
    attn_mfma<<<dim3((SLEN / ABQ) * BATCH * NHEAD), 512, 0, stream>>>(qkvh, vals);

    // 4) out = vals @ w_o^T + b_o -> fp32; 128x64 tiles: 512 blocks, 2/CU
    gemm_db<64, false><<<dim3(DMODEL / 64, M / 128), 256, 0, stream>>>(
        vals, wo, b_o, out, M, DMODEL, DMODEL);
}

// Round 6
// 219.055 us; speedup vs baseline: 1.0567x; 1.0567x over previous
//
#include <hip/hip_runtime.h>
#include <hip/hip_bf16.h>
#include <math.h>

// Problem constants
#define BATCH 2
#define SLEN  2048
#define DIN   1024
#define DMODEL 1024
#define NHEAD 16
#define HD    64
#define E3    3072   // 3*DMODEL, row width of qkv

typedef unsigned short us;
typedef _Float16 f16;
typedef __attribute__((ext_vector_type(8))) _Float16 f16x8;
typedef __attribute__((ext_vector_type(8))) unsigned short us8;
typedef __attribute__((ext_vector_type(4))) unsigned short us4;
typedef __attribute__((ext_vector_type(4))) float f32x4;
typedef __attribute__((ext_vector_type(16))) float f32x16;
typedef __attribute__((ext_vector_type(4))) unsigned int u32x4;

// 0.125 (1/sqrt(HD)) * log2(e): folded into Q at qkv-GEMM epilogue so the
// attention softmax is a bare exp2 of the raw MFMA score.
#define QSCALE 0.18033688011112042f

__device__ __forceinline__ us f16bits(float x) {
    const f16 h = (f16)x;
    return __builtin_bit_cast(us, h);
}

__device__ __forceinline__ unsigned int pkrtz(float a, float b) {
    return __builtin_bit_cast(unsigned int, __builtin_amdgcn_cvt_pkrtz(a, b));
}

// v_permlane32_swap_b32: a' = {a.lo, b.lo}, b' = {a.hi, b.hi}
__device__ __forceinline__ void plswap(unsigned int& a, unsigned int& b) {
    asm volatile("v_permlane32_swap_b32 %0, %1" : "+v"(a), "+v"(b));
}

__device__ __forceinline__ void barrier_raw() {
    asm volatile("s_barrier" ::: "memory");
}

// async 16B global->LDS (lane i deposits at ldsbase + i*16)
#define GLL16(g, l)                                                                     \
    __builtin_amdgcn_global_load_lds((const __attribute__((address_space(1))) unsigned int*)(g), \
                                     (__attribute__((address_space(3))) unsigned int*)(l), 16, 0, 0)

// ---------------- fp32 -> fp16 for x, w_qkv, w_o in one launch ----------------
__global__ __launch_bounds__(256) void cvt3_f16(
    const float* __restrict__ x, us* __restrict__ ox, int nx,
    const float* __restrict__ wq, us* __restrict__ owq, int nq,
    const float* __restrict__ wo, us* __restrict__ owo)
{
    int i = (blockIdx.x * 256 + threadIdx.x) * 8;
    const float* s;
    us* o;
    if (i < nx)           { s = x;  o = ox; }
    else if (i < nx + nq) { s = wq; o = owq; i -= nx; }
    else                  { s = wo; o = owo; i -= nx + nq; }
    const float4 f0 = *(const float4*)&s[i];
    const float4 f1 = *(const float4*)&s[i + 4];
    const float v[8] = {f0.x, f0.y, f0.z, f0.w, f1.x, f1.y, f1.z, f1.w};
    us8 h;
#pragma unroll
    for (int j = 0; j < 8; ++j) h[j] = f16bits(v[j]);
    *(us8*)&o[i] = h;
}

// ---------------- 128xBN double-buffered counted-vmcnt MFMA GEMM ----------------
// (unchanged from R3; see comments there)
#define GBK 64
#define GNT (DIN / GBK)   // 16 (both GEMMs have K=1024)

template <int BN, bool QKV_OUT>
__global__ __launch_bounds__(256) void gemm_db(
    const us* __restrict__ Am, const us* __restrict__ Bm,
    const float* __restrict__ bias, void* __restrict__ Cout,
    int M, int N, int K)
{
    constexpr int NJ  = BN / 32;    // n-frags per wave (4 or 2)
    constexpr int BGL = BN / 32;    // B-staging GLLs per wave (4 or 2)
    __shared__ __align__(16) us ldsA[2 * 128 * 64];
    __shared__ __align__(16) us ldsB[2 * BN * 64];

    const int t    = threadIdx.x;
    const int lane = t & 63;
    const int w    = t >> 6;        // wave 0..3
    const int ml   = lane & 15;
    const int quad = lane >> 4;
    const int msk  = ml & 7;
    const int wm   = w >> 1;
    const int wn   = w & 1;

    // XCD-aware bijective block swizzle (nwg % 8 == 0 for both grids)
    const int nbx = N / BN;
    const int nwg = (M >> 7) * nbx;
    int wg = blockIdx.y * nbx + blockIdx.x;
    wg = (wg & 7) * (nwg >> 3) + (wg >> 3);
    const int m0 = (wg / nbx) * 128;
    const int n0 = (wg % nbx) * BN;

    const int r8  = lane >> 3;
    const int xsw = ((lane & 7) ^ r8) * 8;
    const us* pA = Am + (size_t)(m0 + w * 32 + r8) * K + xsw;
    const int brow = (BN == 128) ? w * 32 : w * 16;
    const us* pB = Bm + (size_t)(n0 + brow + r8) * K + xsw;

#define STG_A(d, kk) do { _Pragma("unroll") for (int g = 0; g < 4; ++g) \
    GLL16(pA + (size_t)(8 * g) * K + (kk), &ldsA[(d) * 8192 + w * 2048 + g * 512]); } while (0)
#define STG_B(d, kk) do { _Pragma("unroll") for (int g = 0; g < BGL; ++g) \
    GLL16(pB + (size_t)(8 * g) * K + (kk), &ldsB[(d) * (BN * 64) + brow * 64 + g * 512]); } while (0)

#define LDA(d, mi, ks) __builtin_bit_cast(f16x8, *(const us8*)&ldsA[(d) * 8192 + (wm * 64 + (mi) * 16 + ml) * 64 + (((quad ^ msk) ^ ((ks) << 2)) * 8)])
#define LDB(d, nj, ks) __builtin_bit_cast(f16x8, *(const us8*)&ldsB[(d) * (BN * 64) + (wn * (BN / 2) + (nj) * 16 + ml) * 64 + (((quad ^ msk) ^ ((ks) << 2)) * 8)])

#define WAIT_BGL() do { if constexpr (BN == 128) asm volatile("s_waitcnt vmcnt(4)" ::: "memory"); \
                        else                     asm volatile("s_waitcnt vmcnt(2)" ::: "memory"); } while (0)

    f32x4 acc[4][NJ];
#pragma unroll
    for (int i = 0; i < 4; ++i)
#pragma unroll
        for (int j = 0; j < NJ; ++j) {
            acc[i][j][0] = 0.f; acc[i][j][1] = 0.f; acc[i][j][2] = 0.f; acc[i][j][3] = 0.f;
        }

    STG_A(0, 0); STG_B(0, 0);
    STG_B(1, GBK);
    WAIT_BGL();
    barrier_raw();

    for (int tt = 0; tt < GNT; ++tt) {
        const int d = tt & 1, e = d ^ 1;

        if (tt + 1 < GNT) STG_A(e, (tt + 1) * GBK);
        f16x8 bf[2][NJ];
#pragma unroll
        for (int ks = 0; ks < 2; ++ks)
#pragma unroll
            for (int nj = 0; nj < NJ; ++nj)
                bf[ks][nj] = LDB(d, nj, ks);
        f16x8 a0[2][2];
#pragma unroll
        for (int mi = 0; mi < 2; ++mi) {
            a0[mi][0] = LDA(d, mi, 0);
            a0[mi][1] = LDA(d, mi, 1);
        }
        __builtin_amdgcn_s_setprio(1);
#pragma unroll
        for (int ks = 0; ks < 2; ++ks)
#pragma unroll
            for (int nj = 0; nj < NJ; ++nj)
#pragma unroll
                for (int mi = 0; mi < 2; ++mi)
                    acc[mi][nj] = __builtin_amdgcn_mfma_f32_16x16x32_f16(a0[mi][ks], bf[ks][nj], acc[mi][nj], 0, 0, 0);
        __builtin_amdgcn_s_setprio(0);
        barrier_raw();

        if (tt + 2 < GNT) STG_B(d, (tt + 2) * GBK);
        f16x8 a1[2][2];
#pragma unroll
        for (int mi = 0; mi < 2; ++mi) {
            a1[mi][0] = LDA(d, mi + 2, 0);
            a1[mi][1] = LDA(d, mi + 2, 1);
        }
        __builtin_amdgcn_s_setprio(1);
#pragma unroll
        for (int ks = 0; ks < 2; ++ks)
#pragma unroll
            for (int nj = 0; nj < NJ; ++nj)
#pragma unroll
                for (int mi = 0; mi < 2; ++mi)
                    acc[mi + 2][nj] = __builtin_amdgcn_mfma_f32_16x16x32_f16(a1[mi][ks], bf[ks][nj], acc[mi + 2][nj], 0, 0, 0);
        __builtin_amdgcn_s_setprio(0);

        if (tt + 2 < GNT)      WAIT_BGL();
        else if (tt + 1 < GNT) asm volatile("s_waitcnt vmcnt(0)" ::: "memory");
        barrier_raw();
    }

    float bj[NJ], cs[NJ];
#pragma unroll
    for (int nj = 0; nj < NJ; ++nj) {
        const int col = n0 + wn * (BN / 2) + nj * 16 + ml;
        bj[nj] = bias[col];
        cs[nj] = (QKV_OUT && (col % 192) < 64) ? QSCALE : 1.0f;
    }
#pragma unroll
    for (int mi = 0; mi < 4; ++mi) {
#pragma unroll
        for (int r = 0; r < 4; ++r) {
            const size_t rowoff = (size_t)(m0 + wm * 64 + mi * 16 + quad * 4 + r) * N;
#pragma unroll
            for (int nj = 0; nj < NJ; ++nj) {
                const int col = n0 + wn * (BN / 2) + nj * 16 + ml;
                const float v = (acc[mi][nj][r] + bj[nj]) * cs[nj];
                if (QKV_OUT) ((us*)Cout)[rowoff + col] = f16bits(v);
                else         ((float*)Cout)[rowoff + col] = v;
            }
        }
    }
#undef STG_A
#undef STG_B
#undef LDA
#undef LDB
#undef WAIT_BGL
}

// ---------------- MFMA flash attention: K direct from global (L2), V-only LDS ----------------
// R5 structure with the spill fixed: __launch_bounds__(512, 2) -> 128-VGPR cap
// (R5's (512,4) was interpreted as 4 blocks/CU -> 64-VGPR cap -> ~60 regs
// spilled -> 25 MB scratch traffic/dispatch -> 2x regression).
// Register-pressure trims: V-write moved to TOP of chunk (vv dead during QK
// peak), exp2/pack in two scoped halves of 8, lp[2].
// Chunk body (ONE barrier per chunk):
//   write V(c+1)->buf e (readers retired at chunk-entry barrier)
//   QK(c) from K-regs; exp2+pack (T12, scoped halves)
//   reload K(c+1)->regs; prefetch V(c+2)->regs
//   PV(c) from buf d; barrier
#define ABQ 128
#define ACH 64
#define NCH (SLEN / ACH)    // 32
#define NCH2 (NCH / 2)      // 16 chunks per split
#define LQA 72              // LDS row stride in fp16 elems
#define OSTR 68             // combine-scratch row stride in f32

__global__ __launch_bounds__(512, 2) void attn_mfma(
    const us* __restrict__ qkvh, us* __restrict__ vals)
{
    // Q 9216 | V dbuf 2 x (2 splits x 4608) = 27648 us = 55296 B (2 blk/CU)
    __shared__ __align__(16) us smem[27648];
    us* const Qs = smem;            // [0, 9216)
    us* const Vb0 = smem + 9216;    // [9216, 18432)
    us* const Vb1 = smem + 18432;   // [18432, 27648)

    const int t    = threadIdx.x;
    const int lane = t & 63;
    const int w    = t >> 6;        // wave 0..7
    const int sp   = w >> 2;        // key split 0/1
    const int wq4  = w & 3;         // q-group within split
    const int t2   = t & 255;       // thread id within split
    const int m32  = lane & 31;
    const int half = lane >> 5;

    // XCD-owning decomposition: xcd = wg&7; bh = ((wg>>7)<<3)|xcd; qi = (wg>>3)&15
    const int wg  = blockIdx.x;
    const int s9  = wg >> 3;
    const int bh  = ((s9 >> 4) << 3) | (wg & 7);
    const int b   = bh >> 4;
    const int h   = bh & 15;
    const int q0  = (s9 & 15) * ABQ;

    const size_t base = (size_t)b * SLEN * E3;
    const int qoff = h * 192;

    // V staging map (within split)
    const int k2  = t2 & 31;          // V: key PAIR (2*k2, 2*k2+1)
    const int d0v = (t2 >> 5) * 8;    // V: 8 dims/thread

    us* const myV0 = Vb0 + sp * 4608;
    us* const myV1 = Vb1 + sp * 4608;
    const int cg0 = sp * NCH2;

    // per-lane K fragment pointer: row m32 (+ kt*32 + chunk*64), col half*8 (+16s)
    const us* const gK = &qkvh[base + (size_t)m32 * E3 + qoff + 64 + half * 8];

    us8 kr[2][4];
#define LOADK(cgi) do { _Pragma("unroll") for (int kt = 0; kt < 2; ++kt) \
    _Pragma("unroll") for (int s = 0; s < 4; ++s) \
        kr[kt][s] = *(const us8*)&gK[(size_t)((cgi) * ACH + kt * 32) * E3 + 16 * s]; } while (0)

    // ---- stage Q (128 q x 64 d): 16 elems / thread ----
    {
        const int row = t >> 2;
        const int c0q = (t & 3) * 16;
        const us* g = &qkvh[base + (size_t)(q0 + row) * E3 + qoff + c0q];
        *(us8*)&Qs[row * LQA + c0q]     = *(const us8*)g;
        *(us8*)&Qs[row * LQA + c0q + 8] = *(const us8*)(g + 8);
    }

    // ---- prologue: K(0)->regs; V(0)->buf0; V(1)->regs ----
    LOADK(cg0);
    us8 vv0, vv1;
    {
        const us* gV = &qkvh[base + (size_t)(cg0 * ACH + 2 * k2) * E3 + qoff + 128 + d0v];
        vv0 = *(const us8*)gV; vv1 = *(const us8*)(gV + E3);
    }
#pragma unroll
    for (int j = 0; j < 8; ++j) {
        const unsigned int pv = (unsigned int)vv0[j] | ((unsigned int)vv1[j] << 16);
        *(unsigned int*)&myV0[(d0v + j) * LQA + 2 * k2] = pv;
    }
    {
        const us* gV = &qkvh[base + (size_t)((cg0 + 1) * ACH + 2 * k2) * E3 + qoff + 128 + d0v];
        vv0 = *(const us8*)gV; vv1 = *(const us8*)(gV + E3);
    }
    __syncthreads();   // Q + V(0) visible to all waves

    // Q B-frags: B[k=dim][n=q], q = wq4*32 + m32
    f16x8 aq[4];
#pragma unroll
    for (int s = 0; s < 4; ++s)
        aq[s] = __builtin_bit_cast(f16x8, *(const us8*)&Qs[(wq4 * 32 + m32) * LQA + half * 8 + 16 * s]);

    f32x16 O[2];
#pragma unroll
    for (int dt = 0; dt < 2; ++dt)
#pragma unroll
        for (int r = 0; r < 16; ++r) O[dt][r] = 0.f;
    float lp[2] = {0.f, 0.f};

    for (int c = 0; c < NCH2; ++c) {
        us* const Vrd = (c & 1) ? myV1 : myV0;
        us* const Vwr = (c & 1) ? myV0 : myV1;

        // ---- write V(c+1) FIRST (buffer's readers PV(c-1) retired at the
        //      chunk-entry barrier); frees vv before the QK register peak ----
        if (c + 1 < NCH2) {
#pragma unroll
            for (int j = 0; j < 8; ++j) {
                const unsigned int pv = (unsigned int)vv0[j] | ((unsigned int)vv1[j] << 16);
                *(unsigned int*)&Vwr[(d0v + j) * LQA + 2 * k2] = pv;
            }
        }

        // ---- S^T = K.Q^T from K-regs; exp2; T12 pack (scoped halves of 8) ----
        f16x8 pf[4];
#pragma unroll
        for (int kt = 0; kt < 2; ++kt) {
            f32x16 z;
#pragma unroll
            for (int r = 0; r < 16; ++r) z[r] = 0.f;
#pragma unroll
            for (int s = 0; s < 4; ++s)
                z = __builtin_amdgcn_mfma_f32_32x32x16_f16(
                        __builtin_bit_cast(f16x8, kr[kt][s]), aq[s], z, 0, 0, 0);
            {   // regs 0..7 -> pf[2kt]
                float p[8];
#pragma unroll
                for (int r = 0; r < 8; ++r) {
                    p[r] = __builtin_amdgcn_exp2f(z[r]);
                    lp[r & 1] += p[r];
                }
                unsigned int a0 = pkrtz(p[0], p[1]), a1 = pkrtz(p[2], p[3]);
                unsigned int b0 = pkrtz(p[4], p[5]), b1 = pkrtz(p[6], p[7]);
                plswap(a0, b0); plswap(a1, b1);
                pf[2 * kt] = __builtin_bit_cast(f16x8, (u32x4){a0, a1, b0, b1});
            }
            {   // regs 8..15 -> pf[2kt+1]
                float p[8];
#pragma unroll
                for (int r = 0; r < 8; ++r) {
                    p[r] = __builtin_amdgcn_exp2f(z[8 + r]);
                    lp[r & 1] += p[r];
                }
                unsigned int e0 = pkrtz(p[0], p[1]), e1 = pkrtz(p[2], p[3]);
                unsigned int f0 = pkrtz(p[4], p[5]), f1 = pkrtz(p[6], p[7]);
                plswap(e0, f0); plswap(e1, f1);
                pf[2 * kt + 1] = __builtin_bit_cast(f16x8, (u32x4){e0, e1, f0, f1});
            }
        }

        // ---- reload K-regs for next chunk (WAR on kr; lands during PV+barrier) ----
        if (c + 1 < NCH2) LOADK(cg0 + c + 1);
        // ---- prefetch V(c+2) -> regs (written at top of chunk c+1) ----
        if (c + 2 < NCH2) {
            const us* gV = &qkvh[base + (size_t)((cg0 + c + 2) * ACH + 2 * k2) * E3 + qoff + 128 + d0v];
            vv0 = *(const us8*)gV; vv1 = *(const us8*)(gV + E3);
        }

        // ---- O^T += V^T.P^T ----
#pragma unroll
        for (int dt = 0; dt < 2; ++dt) {
#pragma unroll
            for (int s = 0; s < 4; ++s) {
                const f16x8 av = __builtin_bit_cast(f16x8, *(const us8*)&Vrd[(dt * 32 + m32) * LQA + half * 8 + 16 * s]);
                O[dt] = __builtin_amdgcn_mfma_f32_32x32x16_f16(av, pf[s], O[dt], 0, 0, 0);
            }
        }

        __syncthreads();   // PV(c) V-reads retired; V(c+1) visible next chunk
    }

    const float lpart = lp[0] + lp[1];
    const float l = lpart + __shfl_xor(lpart, 32);
    const int ql = wq4 * 32 + m32;

    // ---- epilogue: combine the two key-splits through LDS (Q/V areas dead) ----
    __syncthreads();
    float* const Osc = (float*)smem;         // 128 x OSTR f32 (34816 B)
    float* const lsc = Osc + ABQ * OSTR;     // 128 f32

    if (sp == 1) {
#pragma unroll
        for (int dt = 0; dt < 2; ++dt) {
#pragma unroll
            for (int g = 0; g < 4; ++g) {
                const f32x4 o4 = {O[dt][g * 4], O[dt][g * 4 + 1], O[dt][g * 4 + 2], O[dt][g * 4 + 3]};
                *(f32x4*)&Osc[ql * OSTR + dt * 32 + 8 * g + 4 * half] = o4;
            }
        }
        if (half == 0) lsc[ql] = l;
    }
    __syncthreads();
    if (sp == 0) {
        const float rl = 1.0f / (l + lsc[ql]);
        const int sq = q0 + ql;
        const size_t rowbase = (size_t)(b * SLEN + sq) * DMODEL + h * HD;
#pragma unroll
        for (int dt = 0; dt < 2; ++dt) {
#pragma unroll
            for (int g = 0; g < 4; ++g) {
                const f32x4 part = *(const f32x4*)&Osc[ql * OSTR + dt * 32 + 8 * g + 4 * half];
                us4 o4;
#pragma unroll
                for (int r2 = 0; r2 < 4; ++r2)
                    o4[r2] = f16bits((O[dt][g * 4 + r2] + part[r2]) * rl);
                *(us4*)&vals[rowbase + dt * 32 + 8 * g + 4 * half] = o4;
            }
        }
    }
#undef LOADK
}

// ---------------- launch ----------------
extern "C" void kernel_launch(void* const* d_in, const int* in_sizes, int n_in,
                              void* d_out, int out_size, void* d_ws, size_t ws_size,
                              hipStream_t stream) {
    const float* x     = (const float*)d_in[0];
    const float* w_qkv = (const float*)d_in[1];
    const float* b_qkv = (const float*)d_in[2];
    const float* w_o   = (const float*)d_in[3];
    const float* b_o   = (const float*)d_in[4];
    float* out = (float*)d_out;

    const int M   = BATCH * SLEN;        // 4096
    const int XN  = M * DIN;             // 4,194,304
    const int WQN = E3 * DIN;            // 3,145,728
    const int WON = DMODEL * DMODEL;     // 1,048,576
    const size_t QKVN = (size_t)BATCH * SLEN * E3;

    us* qkvh = (us*)d_ws;                // fp16 qkv [QKVN]
    us* xh   = qkvh + QKVN;              // fp16 x [XN], reused for vals
    us* wq   = xh + XN;                  // fp16 w_qkv [WQN]
    us* wo   = wq + WQN;                 // fp16 w_o [WON]

    // 1) fp32 -> fp16 conversions, one launch
    cvt3_f16<<<dim3((XN + WQN + WON) / 2048), 256, 0, stream>>>(
        x, xh, XN, w_qkv, wq, WQN, w_o, wo);

    // 2) qkv = x @ w_qkv^T + b_qkv -> fp16 (Q cols pre-scaled by QSCALE)
    gemm_db<128, true><<<dim3(E3 / 128, M / 128), 256, 0, stream>>>(
        xh, wq, b_qkv, qkvh, M, E3, DIN);

    // 3) attention -> vals fp16 (reuse x plane; x is dead); 1D grid, XCD-owned bh
    us* vals = xh;
    attn_mfma<<<dim3((SLEN / ABQ) * BATCH * NHEAD), 512, 0, stream>>>(qkvh, vals);

    // 4) out = vals @ w_o^T + b_o -> fp32; 128x64 tiles: 512 blocks, 2/CU
    gemm_db<64, false><<<dim3(DMODEL / 64, M / 128), 256, 0, stream>>>(
        vals, wo, b_o, out, M, DMODEL, DMODEL);
}

// Round 7
// 185.933 us; speedup vs baseline: 1.2449x; 1.1781x over previous
//
#include <hip/hip_runtime.h>
#include <hip/hip_bf16.h>
#include <math.h>

// Problem constants
#define BATCH 2
#define SLEN  2048
#define DIN   1024
#define DMODEL 1024
#define NHEAD 16
#define HD    64
#define E3    3072   // 3*DMODEL, row width of qkv

typedef unsigned short us;
typedef _Float16 f16;
typedef __attribute__((ext_vector_type(8))) _Float16 f16x8;
typedef __attribute__((ext_vector_type(8))) unsigned short us8;
typedef __attribute__((ext_vector_type(4))) unsigned short us4;
typedef __attribute__((ext_vector_type(4))) float f32x4;
typedef __attribute__((ext_vector_type(16))) float f32x16;
typedef __attribute__((ext_vector_type(4))) unsigned int u32x4;

// 0.125 (1/sqrt(HD)) * log2(e): folded into Q at qkv-GEMM epilogue so the
// attention softmax is a bare exp2 of the raw MFMA score.
#define QSCALE 0.18033688011112042f

__device__ __forceinline__ us f16bits(float x) {
    const f16 h = (f16)x;
    return __builtin_bit_cast(us, h);
}

__device__ __forceinline__ unsigned int pkrtz(float a, float b) {
    return __builtin_bit_cast(unsigned int, __builtin_amdgcn_cvt_pkrtz(a, b));
}

// v_permlane32_swap_b32: a' = {a.lo, b.lo}, b' = {a.hi, b.hi}
__device__ __forceinline__ void plswap(unsigned int& a, unsigned int& b) {
    asm volatile("v_permlane32_swap_b32 %0, %1" : "+v"(a), "+v"(b));
}

__device__ __forceinline__ void barrier_raw() {
    asm volatile("s_barrier" ::: "memory");
}

// async 16B global->LDS (lane i deposits at ldsbase + i*16)
#define GLL16(g, l)                                                                     \
    __builtin_amdgcn_global_load_lds((const __attribute__((address_space(1))) unsigned int*)(g), \
                                     (__attribute__((address_space(3))) unsigned int*)(l), 16, 0, 0)

// ---------------- fp32 -> fp16 for x, w_qkv, w_o in one launch ----------------
__global__ __launch_bounds__(256) void cvt3_f16(
    const float* __restrict__ x, us* __restrict__ ox, int nx,
    const float* __restrict__ wq, us* __restrict__ owq, int nq,
    const float* __restrict__ wo, us* __restrict__ owo)
{
    int i = (blockIdx.x * 256 + threadIdx.x) * 8;
    const float* s;
    us* o;
    if (i < nx)           { s = x;  o = ox; }
    else if (i < nx + nq) { s = wq; o = owq; i -= nx; }
    else                  { s = wo; o = owo; i -= nx + nq; }
    const float4 f0 = *(const float4*)&s[i];
    const float4 f1 = *(const float4*)&s[i + 4];
    const float v[8] = {f0.x, f0.y, f0.z, f0.w, f1.x, f1.y, f1.z, f1.w};
    us8 h;
#pragma unroll
    for (int j = 0; j < 8; ++j) h[j] = f16bits(v[j]);
    *(us8*)&o[i] = h;
}

// ---------------- 128xBN double-buffered counted-vmcnt MFMA GEMM ----------------
// (unchanged from R3; see comments there)
#define GBK 64
#define GNT (DIN / GBK)   // 16 (both GEMMs have K=1024)

template <int BN, bool QKV_OUT>
__global__ __launch_bounds__(256) void gemm_db(
    const us* __restrict__ Am, const us* __restrict__ Bm,
    const float* __restrict__ bias, void* __restrict__ Cout,
    int M, int N, int K)
{
    constexpr int NJ  = BN / 32;    // n-frags per wave (4 or 2)
    constexpr int BGL = BN / 32;    // B-staging GLLs per wave (4 or 2)
    __shared__ __align__(16) us ldsA[2 * 128 * 64];
    __shared__ __align__(16) us ldsB[2 * BN * 64];

    const int t    = threadIdx.x;
    const int lane = t & 63;
    const int w    = t >> 6;        // wave 0..3
    const int ml   = lane & 15;
    const int quad = lane >> 4;
    const int msk  = ml & 7;
    const int wm   = w >> 1;
    const int wn   = w & 1;

    // XCD-aware bijective block swizzle (nwg % 8 == 0 for both grids)
    const int nbx = N / BN;
    const int nwg = (M >> 7) * nbx;
    int wg = blockIdx.y * nbx + blockIdx.x;
    wg = (wg & 7) * (nwg >> 3) + (wg >> 3);
    const int m0 = (wg / nbx) * 128;
    const int n0 = (wg % nbx) * BN;

    const int r8  = lane >> 3;
    const int xsw = ((lane & 7) ^ r8) * 8;
    const us* pA = Am + (size_t)(m0 + w * 32 + r8) * K + xsw;
    const int brow = (BN == 128) ? w * 32 : w * 16;
    const us* pB = Bm + (size_t)(n0 + brow + r8) * K + xsw;

#define STG_A(d, kk) do { _Pragma("unroll") for (int g = 0; g < 4; ++g) \
    GLL16(pA + (size_t)(8 * g) * K + (kk), &ldsA[(d) * 8192 + w * 2048 + g * 512]); } while (0)
#define STG_B(d, kk) do { _Pragma("unroll") for (int g = 0; g < BGL; ++g) \
    GLL16(pB + (size_t)(8 * g) * K + (kk), &ldsB[(d) * (BN * 64) + brow * 64 + g * 512]); } while (0)

#define LDA(d, mi, ks) __builtin_bit_cast(f16x8, *(const us8*)&ldsA[(d) * 8192 + (wm * 64 + (mi) * 16 + ml) * 64 + (((quad ^ msk) ^ ((ks) << 2)) * 8)])
#define LDB(d, nj, ks) __builtin_bit_cast(f16x8, *(const us8*)&ldsB[(d) * (BN * 64) + (wn * (BN / 2) + (nj) * 16 + ml) * 64 + (((quad ^ msk) ^ ((ks) << 2)) * 8)])

#define WAIT_BGL() do { if constexpr (BN == 128) asm volatile("s_waitcnt vmcnt(4)" ::: "memory"); \
                        else                     asm volatile("s_waitcnt vmcnt(2)" ::: "memory"); } while (0)

    f32x4 acc[4][NJ];
#pragma unroll
    for (int i = 0; i < 4; ++i)
#pragma unroll
        for (int j = 0; j < NJ; ++j) {
            acc[i][j][0] = 0.f; acc[i][j][1] = 0.f; acc[i][j][2] = 0.f; acc[i][j][3] = 0.f;
        }

    STG_A(0, 0); STG_B(0, 0);
    STG_B(1, GBK);
    WAIT_BGL();
    barrier_raw();

    for (int tt = 0; tt < GNT; ++tt) {
        const int d = tt & 1, e = d ^ 1;

        if (tt + 1 < GNT) STG_A(e, (tt + 1) * GBK);
        f16x8 bf[2][NJ];
#pragma unroll
        for (int ks = 0; ks < 2; ++ks)
#pragma unroll
            for (int nj = 0; nj < NJ; ++nj)
                bf[ks][nj] = LDB(d, nj, ks);
        f16x8 a0[2][2];
#pragma unroll
        for (int mi = 0; mi < 2; ++mi) {
            a0[mi][0] = LDA(d, mi, 0);
            a0[mi][1] = LDA(d, mi, 1);
        }
        __builtin_amdgcn_s_setprio(1);
#pragma unroll
        for (int ks = 0; ks < 2; ++ks)
#pragma unroll
            for (int nj = 0; nj < NJ; ++nj)
#pragma unroll
                for (int mi = 0; mi < 2; ++mi)
                    acc[mi][nj] = __builtin_amdgcn_mfma_f32_16x16x32_f16(a0[mi][ks], bf[ks][nj], acc[mi][nj], 0, 0, 0);
        __builtin_amdgcn_s_setprio(0);
        barrier_raw();

        if (tt + 2 < GNT) STG_B(d, (tt + 2) * GBK);
        f16x8 a1[2][2];
#pragma unroll
        for (int mi = 0; mi < 2; ++mi) {
            a1[mi][0] = LDA(d, mi + 2, 0);
            a1[mi][1] = LDA(d, mi + 2, 1);
        }
        __builtin_amdgcn_s_setprio(1);
#pragma unroll
        for (int ks = 0; ks < 2; ++ks)
#pragma unroll
            for (int nj = 0; nj < NJ; ++nj)
#pragma unroll
                for (int mi = 0; mi < 2; ++mi)
                    acc[mi + 2][nj] = __builtin_amdgcn_mfma_f32_16x16x32_f16(a1[mi][ks], bf[ks][nj], acc[mi + 2][nj], 0, 0, 0);
        __builtin_amdgcn_s_setprio(0);

        if (tt + 2 < GNT)      WAIT_BGL();
        else if (tt + 1 < GNT) asm volatile("s_waitcnt vmcnt(0)" ::: "memory");
        barrier_raw();
    }

    float bj[NJ], cs[NJ];
#pragma unroll
    for (int nj = 0; nj < NJ; ++nj) {
        const int col = n0 + wn * (BN / 2) + nj * 16 + ml;
        bj[nj] = bias[col];
        cs[nj] = (QKV_OUT && (col % 192) < 64) ? QSCALE : 1.0f;
    }
#pragma unroll
    for (int mi = 0; mi < 4; ++mi) {
#pragma unroll
        for (int r = 0; r < 4; ++r) {
            const size_t rowoff = (size_t)(m0 + wm * 64 + mi * 16 + quad * 4 + r) * N;
#pragma unroll
            for (int nj = 0; nj < NJ; ++nj) {
                const int col = n0 + wn * (BN / 2) + nj * 16 + ml;
                const float v = (acc[mi][nj][r] + bj[nj]) * cs[nj];
                if (QKV_OUT) ((us*)Cout)[rowoff + col] = f16bits(v);
                else         ((float*)Cout)[rowoff + col] = v;
            }
        }
    }
#undef STG_A
#undef STG_B
#undef LDA
#undef LDB
#undef WAIT_BGL
}

// ---------------- MFMA flash attention, 4-blocks/CU via Q-overlay ----------------
// R1 chunk structure (best measured: key-split 8 waves, staged coalesced K/V,
// T12 in-register P, exact split combine) + T1 XCD-owned grid. NEW (R7):
// Q's 18 KB staging area is OVERLAID with Ks -- Q is read once into registers
// at the prologue, then the area hosts K. LDS 55.3 -> 36.9 KB, which with
// VGPR<=64 gives 4 blocks/CU (32 waves/CU), doubling cross-block overlap of
// the serialized pipes (MFMA ~14us + LDS ~20us + TRANS ~7us + VALU ~5us).
// R6 lesson encoded: K must be staged via the 4-threads/row COALESCED global
// loads + LDS; per-lane strided K loads (stride 6KB) are 32-line gathers.
#define ABQ 128
#define ACH 64
#define NCH (SLEN / ACH)    // 32
#define NCH2 (NCH / 2)      // 16 chunks per split
#define LQA 72              // LDS row stride in fp16 elems
#define OSTR 68             // combine-scratch row stride in f32

__global__ __launch_bounds__(512, 4) void attn_mfma(
    const us* __restrict__ qkvh, us* __restrict__ vals)
{
    // 36 KB total: Q staged in [0,9216) then dead; Ks overlays [0,9216);
    // Vt [9216,18432). Epilogue Osc (35.3 KB) reuses the whole block.
    __shared__ __align__(16) us smem[18432];
    us* const Ks = smem;            // [0, 9216)  (2 splits x 4608)
    us* const Vt = smem + 9216;     // [9216, 18432)

    const int t    = threadIdx.x;
    const int lane = t & 63;
    const int w    = t >> 6;        // wave 0..7
    const int sp   = w >> 2;        // key split 0/1
    const int wq4  = w & 3;         // q-group within split
    const int t2   = t & 255;       // thread id within split
    const int m32  = lane & 31;
    const int half = lane >> 5;

    // XCD-owning decomposition: xcd = wg&7; bh = ((wg>>7)<<3)|xcd; qi = (wg>>3)&15
    const int wg  = blockIdx.x;
    const int s9  = wg >> 3;
    const int bh  = ((s9 >> 4) << 3) | (wg & 7);
    const int b   = bh >> 4;
    const int h   = bh & 15;
    const int q0  = (s9 & 15) * ABQ;

    const size_t base = (size_t)b * SLEN * E3;
    const int qoff = h * 192;

    // staging maps (within split)
    const int krA = t2 >> 2;          // K: key 0..63, 16 dims/thread (coalesced)
    const int ksA = (t2 & 3) * 16;
    const int k2  = t2 & 31;          // V: key PAIR (2*k2, 2*k2+1)
    const int d0v = (t2 >> 5) * 8;    // V: 8 dims/thread

    us* const myK = Ks + sp * 4608;
    us* const myV = Vt + sp * 4608;
    const int cg0 = sp * NCH2;

    // ---- issue chunk-0 K/V loads first (hide under Q staging) ----
    us8 kk0, kk1, vv0, vv1;
    {
        const us* gK = &qkvh[base + (size_t)(cg0 * ACH + krA) * E3 + qoff + 64 + ksA];
        kk0 = *(const us8*)gK; kk1 = *(const us8*)(gK + 8);
        const us* gV = &qkvh[base + (size_t)(cg0 * ACH + 2 * k2) * E3 + qoff + 128 + d0v];
        vv0 = *(const us8*)gV; vv1 = *(const us8*)(gV + E3);
    }

    // ---- stage Q (128 q x 64 d) into the Ks area (dies after aq read) ----
    {
        const int row = t >> 2;
        const int c0q = (t & 3) * 16;
        const us* g = &qkvh[base + (size_t)(q0 + row) * E3 + qoff + c0q];
        *(us8*)&smem[row * LQA + c0q]     = *(const us8*)g;
        *(us8*)&smem[row * LQA + c0q + 8] = *(const us8*)(g + 8);
    }
    __syncthreads();

    // Q B-frags: B[k=dim][n=q], q = wq4*32 + m32
    f16x8 aq[4];
#pragma unroll
    for (int s = 0; s < 4; ++s)
        aq[s] = __builtin_bit_cast(f16x8, *(const us8*)&smem[(wq4 * 32 + m32) * LQA + half * 8 + 16 * s]);
    // NOTE: first loop-top barrier separates these Q reads from K(0) writes.

    f32x16 O[2];
#pragma unroll
    for (int dt = 0; dt < 2; ++dt)
#pragma unroll
        for (int r = 0; r < 16; ++r) O[dt][r] = 0.f;
    float lp[2] = {0.f, 0.f};

    for (int c = 0; c < NCH2; ++c) {
        __syncthreads();   // c==0: Q reads retired; else: prev chunk's Ks/Vt consumed
        // ---- regs -> LDS ----
        *(us8*)&myK[krA * LQA + ksA]     = kk0;
        *(us8*)&myK[krA * LQA + ksA + 8] = kk1;
#pragma unroll
        for (int j = 0; j < 8; ++j) {
            const unsigned int pv = (unsigned int)vv0[j] | ((unsigned int)vv1[j] << 16);
            *(unsigned int*)&myV[(d0v + j) * LQA + 2 * k2] = pv;
        }
        __syncthreads();
        // ---- prefetch next chunk (latency hidden behind compute) ----
        if (c + 1 < NCH2) {
            const int cg = cg0 + c + 1;
            const us* gK = &qkvh[base + (size_t)(cg * ACH + krA) * E3 + qoff + 64 + ksA];
            kk0 = *(const us8*)gK; kk1 = *(const us8*)(gK + 8);
            const us* gV = &qkvh[base + (size_t)(cg * ACH + 2 * k2) * E3 + qoff + 128 + d0v];
            vv0 = *(const us8*)gV; vv1 = *(const us8*)(gV + E3);
        }

        // ---- S^T = K.Q^T per key-tile; exp2; T12 pack (scoped halves of 8) ----
        f16x8 pf[4];
#pragma unroll
        for (int kt = 0; kt < 2; ++kt) {
            f32x16 z;
#pragma unroll
            for (int r = 0; r < 16; ++r) z[r] = 0.f;
#pragma unroll
            for (int s = 0; s < 4; ++s) {
                const f16x8 ak = __builtin_bit_cast(f16x8, *(const us8*)&myK[(kt * 32 + m32) * LQA + half * 8 + 16 * s]);
                z = __builtin_amdgcn_mfma_f32_32x32x16_f16(ak, aq[s], z, 0, 0, 0);
            }
            {   // regs 0..7 -> pf[2kt]
                float p[8];
#pragma unroll
                for (int r = 0; r < 8; ++r) {
                    p[r] = __builtin_amdgcn_exp2f(z[r]);
                    lp[r & 1] += p[r];
                }
                unsigned int a0 = pkrtz(p[0], p[1]), a1 = pkrtz(p[2], p[3]);
                unsigned int b0 = pkrtz(p[4], p[5]), b1 = pkrtz(p[6], p[7]);
                plswap(a0, b0); plswap(a1, b1);
                pf[2 * kt] = __builtin_bit_cast(f16x8, (u32x4){a0, a1, b0, b1});
            }
            {   // regs 8..15 -> pf[2kt+1]
                float p[8];
#pragma unroll
                for (int r = 0; r < 8; ++r) {
                    p[r] = __builtin_amdgcn_exp2f(z[8 + r]);
                    lp[r & 1] += p[r];
                }
                unsigned int e0 = pkrtz(p[0], p[1]), e1 = pkrtz(p[2], p[3]);
                unsigned int f0 = pkrtz(p[4], p[5]), f1 = pkrtz(p[6], p[7]);
                plswap(e0, f0); plswap(e1, f1);
                pf[2 * kt + 1] = __builtin_bit_cast(f16x8, (u32x4){e0, e1, f0, f1});
            }
        }

        // ---- O^T += V^T.P^T ----
#pragma unroll
        for (int dt = 0; dt < 2; ++dt) {
#pragma unroll
            for (int s = 0; s < 4; ++s) {
                const f16x8 av = __builtin_bit_cast(f16x8, *(const us8*)&myV[(dt * 32 + m32) * LQA + half * 8 + 16 * s]);
                O[dt] = __builtin_amdgcn_mfma_f32_32x32x16_f16(av, pf[s], O[dt], 0, 0, 0);
            }
        }
    }

    const float lpart = lp[0] + lp[1];
    const float l = lpart + __shfl_xor(lpart, 32);
    const int ql = wq4 * 32 + m32;

    // ---- epilogue: combine the two key-splits through LDS (K/V areas dead) ----
    __syncthreads();
    float* const Osc = (float*)smem;         // 128 x OSTR f32 (34816 B <= 36864)
    float* const lsc = Osc + ABQ * OSTR;     // 128 f32

    if (sp == 1) {
#pragma unroll
        for (int dt = 0; dt < 2; ++dt) {
#pragma unroll
            for (int g = 0; g < 4; ++g) {
                const f32x4 o4 = {O[dt][g * 4], O[dt][g * 4 + 1], O[dt][g * 4 + 2], O[dt][g * 4 + 3]};
                *(f32x4*)&Osc[ql * OSTR + dt * 32 + 8 * g + 4 * half] = o4;
            }
        }
        if (half == 0) lsc[ql] = l;
    }
    __syncthreads();
    if (sp == 0) {
        const float rl = 1.0f / (l + lsc[ql]);
        const int sq = q0 + ql;
        const size_t rowbase = (size_t)(b * SLEN + sq) * DMODEL + h * HD;
#pragma unroll
        for (int dt = 0; dt < 2; ++dt) {
#pragma unroll
            for (int g = 0; g < 4; ++g) {
                const f32x4 part = *(const f32x4*)&Osc[ql * OSTR + dt * 32 + 8 * g + 4 * half];
                us4 o4;
#pragma unroll
                for (int r2 = 0; r2 < 4; ++r2)
                    o4[r2] = f16bits((O[dt][g * 4 + r2] + part[r2]) * rl);
                *(us4*)&vals[rowbase + dt * 32 + 8 * g + 4 * half] = o4;
            }
        }
    }
}

// ---------------- launch ----------------
extern "C" void kernel_launch(void* const* d_in, const int* in_sizes, int n_in,
                              void* d_out, int out_size, void* d_ws, size_t ws_size,
                              hipStream_t stream) {
    const float* x     = (const float*)d_in[0];
    const float* w_qkv = (const float*)d_in[1];
    const float* b_qkv = (const float*)d_in[2];
    const float* w_o   = (const float*)d_in[3];
    const float* b_o   = (const float*)d_in[4];
    float* out = (float*)d_out;

    const int M   = BATCH * SLEN;        // 4096
    const int XN  = M * DIN;             // 4,194,304
    const int WQN = E3 * DIN;            // 3,145,728
    const int WON = DMODEL * DMODEL;     // 1,048,576
    const size_t QKVN = (size_t)BATCH * SLEN * E3;

    us* qkvh = (us*)d_ws;                // fp16 qkv [QKVN]
    us* xh   = qkvh + QKVN;              // fp16 x [XN], reused for vals
    us* wq   = xh + XN;                  // fp16 w_qkv [WQN]
    us* wo   = wq + WQN;                 // fp16 w_o [WON]

    // 1) fp32 -> fp16 conversions, one launch
    cvt3_f16<<<dim3((XN + WQN + WON) / 2048), 256, 0, stream>>>(
        x, xh, XN, w_qkv, wq, WQN, w_o, wo);

    // 2) qkv = x @ w_qkv^T + b_qkv -> fp16 (Q cols pre-scaled by QSCALE)
    gemm_db<128, true><<<dim3(E3 / 128, M / 128), 256, 0, stream>>>(
        xh, wq, b_qkv, qkvh, M, E3, DIN);

    // 3) attention -> vals fp16 (reuse x plane; x is dead); 1D grid, XCD-owned bh
    us* vals = xh;
    attn_mfma<<<dim3((SLEN / ABQ) * BATCH * NHEAD), 512, 0, stream>>>(qkvh, vals);

    // 4) out = vals @ w_o^T + b_o -> fp32; 128x64 tiles: 512 blocks, 2/CU
    gemm_db<64, false><<<dim3(DMODEL / 64, M / 128), 256, 0, stream>>>(
        vals, wo, b_o, out, M, DMODEL, DMODEL);
}